// Round 1
// baseline (1728.944 us; speedup 1.0000x reference)
//
#include <hip/hip_runtime.h>

// Dims (fixed by the problem)
constexpr int Bc  = 4;
constexpr int Lc  = 1024;
constexpr int Dc  = 768;
constexpr int Hc  = 12;
constexpr int NEc = 42;
constexpr int Mc  = 4;
constexpr int Pc  = 512;
constexpr int NLc = 97;
constexpr int Gc  = 12;     // D / 64 groups for the bilinear

// ---------------------------------------------------------------------------
// Kernel A: entity embeddings = logsumexp over M mention-start token embeds
// grid: B*NE blocks, 256 threads
__global__ __launch_bounds__(256) void k_embs(const float* __restrict__ seq,
                                              const int* __restrict__ mpos,
                                              float* __restrict__ embs) {
    int be = blockIdx.x;             // b*NE + e
    int b  = be / NEc;
    const int* pp = mpos + be * Mc;
    int p0 = pp[0] + 1, p1 = pp[1] + 1, p2 = pp[2] + 1, p3 = pp[3] + 1;
    const float* s = seq + (size_t)b * Lc * Dc;
    for (int d = threadIdx.x; d < Dc; d += 256) {
        float x0 = s[(size_t)p0 * Dc + d];
        float x1 = s[(size_t)p1 * Dc + d];
        float x2 = s[(size_t)p2 * Dc + d];
        float x3 = s[(size_t)p3 * Dc + d];
        float mx = fmaxf(fmaxf(x0, x1), fmaxf(x2, x3));
        float sm = expf(x0 - mx) + expf(x1 - mx) + expf(x2 - mx) + expf(x3 - mx);
        embs[(size_t)be * Dc + d] = mx + logf(sm);
    }
}

// ---------------------------------------------------------------------------
// Kernel B: entity attention = mean over M of gathered attention rows
// eatt[b,e,h,l]; grid: (B*NE, H), 256 threads
__global__ __launch_bounds__(256) void k_eatt(const float* __restrict__ att,
                                              const int* __restrict__ mpos,
                                              float* __restrict__ eatt) {
    int be = blockIdx.x, h = blockIdx.y;
    int b = be / NEc;
    const int* pp = mpos + be * Mc;
    const float* a  = att + ((size_t)(b * Hc + h)) * Lc * Lc;
    const float* r0 = a + (size_t)(pp[0] + 1) * Lc;
    const float* r1 = a + (size_t)(pp[1] + 1) * Lc;
    const float* r2 = a + (size_t)(pp[2] + 1) * Lc;
    const float* r3 = a + (size_t)(pp[3] + 1) * Lc;
    float* o = eatt + ((size_t)be * Hc + h) * Lc;
    for (int l = threadIdx.x; l < Lc; l += 256)
        o[l] = 0.25f * (r0[l] + r1[l] + r2[l] + r3[l]);
}

// ---------------------------------------------------------------------------
// Kernel C: per used pair (b,p): q[l] = sum_h ea[i,h,l]*ea[j,h,l];
//           w[l] = q[l] / (sum_l q + H*1e-5)   [= (q/H)/(S/H + 1e-5)]
// grid: B*P blocks, 256 threads (each owns L/256 = 4 l's)
__global__ __launch_bounds__(256) void k_pairw(const float* __restrict__ eatt,
                                               const int* __restrict__ hts,
                                               float* __restrict__ pw) {
    int bp = blockIdx.x;
    int b  = bp / Pc;
    int hi = hts[bp * 2 + 0], ti = hts[bp * 2 + 1];
    const float* ai = eatt + ((size_t)(b * NEc + hi)) * Hc * Lc;
    const float* aj = eatt + ((size_t)(b * NEc + ti)) * Hc * Lc;
    float q[Lc / 256];
    float lsum = 0.f;
    #pragma unroll
    for (int it = 0; it < Lc / 256; ++it) {
        int l = threadIdx.x + it * 256;
        float acc = 0.f;
        #pragma unroll
        for (int h = 0; h < Hc; ++h)
            acc += ai[(size_t)h * Lc + l] * aj[(size_t)h * Lc + l];
        q[it] = acc;
        lsum += acc;
    }
    #pragma unroll
    for (int off = 32; off > 0; off >>= 1)
        lsum += __shfl_down(lsum, off, 64);
    __shared__ float red[4];
    __shared__ float sinv;
    int lane = threadIdx.x & 63, wv = threadIdx.x >> 6;
    if (lane == 0) red[wv] = lsum;
    __syncthreads();
    if (threadIdx.x == 0) {
        float S = red[0] + red[1] + red[2] + red[3];
        sinv = 1.f / (S + 1.2e-4f);   // H * 1e-5
    }
    __syncthreads();
    float* o = pw + (size_t)bp * Lc;
    #pragma unroll
    for (int it = 0; it < Lc / 256; ++it)
        o[threadIdx.x + it * 256] = q[it] * sinv;
}

// ---------------------------------------------------------------------------
// Kernel D: rs[b,p,d] = sum_l pw[b,p,l] * seq[b,l,d]
// Tiled 64x64 f32 GEMM per batch. grid: (P/64, D/64, B), 256 threads (16x16, 4x4 micro)
__global__ __launch_bounds__(256) void k_rs(const float* __restrict__ pw,
                                            const float* __restrict__ seq,
                                            float* __restrict__ rs) {
    int pt = blockIdx.x, dt = blockIdx.y, b = blockIdx.z;
    __shared__ float aT[64][65];
    __shared__ float bT[64][65];
    int tid = threadIdx.x, tx = tid & 15, ty = tid >> 4;
    float acc[4][4] = {};
    const float* wbase = pw + ((size_t)b * Pc + pt * 64) * Lc;
    const float* sbase = seq + (size_t)b * Lc * Dc + dt * 64;
    for (int k0 = 0; k0 < Lc; k0 += 64) {
        #pragma unroll
        for (int i = 0; i < 16; ++i) {
            int idx = tid + i * 256;
            int r = idx >> 6, c = idx & 63;
            aT[r][c] = wbase[(size_t)r * Lc + k0 + c];
            bT[r][c] = sbase[(size_t)(k0 + r) * Dc + c];
        }
        __syncthreads();
        #pragma unroll
        for (int l = 0; l < 64; ++l) {
            float a0 = aT[ty * 4 + 0][l], a1 = aT[ty * 4 + 1][l];
            float a2 = aT[ty * 4 + 2][l], a3 = aT[ty * 4 + 3][l];
            float b0 = bT[l][tx * 4 + 0], b1 = bT[l][tx * 4 + 1];
            float b2 = bT[l][tx * 4 + 2], b3 = bT[l][tx * 4 + 3];
            acc[0][0] += a0 * b0; acc[0][1] += a0 * b1; acc[0][2] += a0 * b2; acc[0][3] += a0 * b3;
            acc[1][0] += a1 * b0; acc[1][1] += a1 * b1; acc[1][2] += a1 * b2; acc[1][3] += a1 * b3;
            acc[2][0] += a2 * b0; acc[2][1] += a2 * b1; acc[2][2] += a2 * b2; acc[2][3] += a2 * b3;
            acc[3][0] += a3 * b0; acc[3][1] += a3 * b1; acc[3][2] += a3 * b2; acc[3][3] += a3 * b3;
        }
        __syncthreads();
    }
    float* o = rs + ((size_t)b * Pc + pt * 64) * Dc + dt * 64;
    #pragma unroll
    for (int i = 0; i < 4; ++i)
        #pragma unroll
        for (int j = 0; j < 4; ++j)
            o[(size_t)(ty * 4 + i) * Dc + tx * 4 + j] = acc[i][j];
}

// ---------------------------------------------------------------------------
// Kernel E: zs = tanh([hs, rs] @ W_head + b_head), zo = tanh([ts, rs] @ W_tail + b_tail)
// A[row,k] is implicit: k<768 -> embs[b, idx, k], else rs[row, k-768]
// grid: (2048/64, D/64, 2), 256 threads, 64x64 tile, 4x4 micro
__global__ __launch_bounds__(256) void k_z(const float* __restrict__ embs,
                                           const float* __restrict__ rs,
                                           const int* __restrict__ hts,
                                           const float* __restrict__ Wh,
                                           const float* __restrict__ bh,
                                           const float* __restrict__ Wt,
                                           const float* __restrict__ bt,
                                           float* __restrict__ zs,
                                           float* __restrict__ zo) {
    int rt = blockIdx.x, dt = blockIdx.y, which = blockIdx.z;
    const float* Wm = which ? Wt : Wh;
    const float* bv = which ? bt : bh;
    float* outp = which ? zo : zs;
    __shared__ float aT[64][65];
    __shared__ float bT[64][65];
    __shared__ int eidx[64];
    int tid = threadIdx.x, tx = tid & 15, ty = tid >> 4;
    int row0 = rt * 64;
    if (tid < 64)
        eidx[tid] = hts[(size_t)(row0 + tid) * 2 + which];
    __syncthreads();
    float acc[4][4] = {};
    for (int k0 = 0; k0 < 2 * Dc; k0 += 64) {
        #pragma unroll
        for (int i = 0; i < 16; ++i) {
            int idx = tid + i * 256;
            int r = idx >> 6, c = idx & 63;
            int bp = row0 + r;
            int k = k0 + c;
            float v;
            if (k < Dc)
                v = embs[((size_t)((bp >> 9) * NEc) + eidx[r]) * Dc + k];
            else
                v = rs[(size_t)bp * Dc + (k - Dc)];
            aT[r][c] = v;
            bT[r][c] = Wm[(size_t)(k0 + r) * Dc + dt * 64 + c];
        }
        __syncthreads();
        #pragma unroll
        for (int l = 0; l < 64; ++l) {
            float a0 = aT[ty * 4 + 0][l], a1 = aT[ty * 4 + 1][l];
            float a2 = aT[ty * 4 + 2][l], a3 = aT[ty * 4 + 3][l];
            float b0 = bT[l][tx * 4 + 0], b1 = bT[l][tx * 4 + 1];
            float b2 = bT[l][tx * 4 + 2], b3 = bT[l][tx * 4 + 3];
            acc[0][0] += a0 * b0; acc[0][1] += a0 * b1; acc[0][2] += a0 * b2; acc[0][3] += a0 * b3;
            acc[1][0] += a1 * b0; acc[1][1] += a1 * b1; acc[1][2] += a1 * b2; acc[1][3] += a1 * b3;
            acc[2][0] += a2 * b0; acc[2][1] += a2 * b1; acc[2][2] += a2 * b2; acc[2][3] += a2 * b3;
            acc[3][0] += a3 * b0; acc[3][1] += a3 * b1; acc[3][2] += a3 * b2; acc[3][3] += a3 * b3;
        }
        __syncthreads();
    }
    #pragma unroll
    for (int i = 0; i < 4; ++i) {
        int row = row0 + ty * 4 + i;
        #pragma unroll
        for (int j = 0; j < 4; ++j) {
            int col = dt * 64 + tx * 4 + j;
            outp[(size_t)row * Dc + col] = tanhf(acc[i][j] + bv[col]);
        }
    }
}

// ---------------------------------------------------------------------------
// Kernel F: grouped bilinear classifier.
// logits[bp,n] = b_bi[n] + sum_{g,x,y} zs[bp,g*64+x]*zo[bp,g*64+y]*W_bi[(g*4096+x*64+y)*97+n]
// grid: (B*P/32 pair tiles, 12 groups); 256 threads = 32 label-lanes x 8 pair-threads
// K split over groups -> partial sums via atomicAdd into zeroed d_out.
__global__ __launch_bounds__(256) void k_bilin(const float* __restrict__ zs,
                                               const float* __restrict__ zo,
                                               const float* __restrict__ wbi,
                                               const float* __restrict__ bbi,
                                               float* __restrict__ out) {
    int pt = blockIdx.x;     // 32-pair tile
    int g  = blockIdx.y;     // bilinear group
    __shared__ float zsl[32][65];
    __shared__ float zol[32][65];
    __shared__ float wl[64][99];
    int tid = threadIdx.x;
    #pragma unroll
    for (int i = 0; i < 8; ++i) {
        int idx = tid + i * 256;
        int p = idx >> 6, c = idx & 63;
        zsl[p][c] = zs[(size_t)(pt * 32 + p) * Dc + g * 64 + c];
        zol[p][c] = zo[(size_t)(pt * 32 + p) * Dc + g * 64 + c];
    }
    int nt = tid & 31, pth = tid >> 5;
    float acc[4][4] = {};
    const float* wg = wbi + (size_t)g * 64 * 64 * NLc;
    for (int x = 0; x < 64; ++x) {
        __syncthreads();                 // previous-iter compute done / zsl ready
        const float* wsrc = wg + (size_t)x * 64 * NLc;
        for (int i = 0; i < 25; ++i) {
            int idx = tid + i * 256;
            if (idx < 64 * NLc) {
                int y = idx / NLc, n = idx - y * NLc;
                wl[y][n] = wsrc[idx];
            }
        }
        __syncthreads();
        float zsx[4];
        #pragma unroll
        for (int i = 0; i < 4; ++i) zsx[i] = zsl[pth * 4 + i][x];
        for (int y = 0; y < 64; ++y) {
            float w0 = wl[y][nt];
            float w1 = wl[y][nt + 32];
            float w2 = wl[y][nt + 64];
            float w3 = (nt == 0) ? wl[y][96] : 0.0f;
            #pragma unroll
            for (int i = 0; i < 4; ++i) {
                float a = zsx[i] * zol[pth * 4 + i][y];
                acc[i][0] += a * w0;
                acc[i][1] += a * w1;
                acc[i][2] += a * w2;
                acc[i][3] += a * w3;
            }
        }
    }
    #pragma unroll
    for (int i = 0; i < 4; ++i) {
        int bp = pt * 32 + pth * 4 + i;
        float* o = out + (size_t)bp * NLc;
        #pragma unroll
        for (int t = 0; t < 3; ++t) {
            int n = nt + 32 * t;
            float v = acc[i][t];
            if (g == 0) v += bbi[n];
            atomicAdd(&o[n], v);
        }
        if (nt == 0) {
            float v = acc[i][3];
            if (g == 0) v += bbi[96];
            atomicAdd(&o[96], v);
        }
    }
}

// ---------------------------------------------------------------------------
extern "C" void kernel_launch(void* const* d_in, const int* in_sizes, int n_in,
                              void* d_out, int out_size, void* d_ws, size_t ws_size,
                              hipStream_t stream) {
    const float* seq  = (const float*)d_in[0];
    const float* att  = (const float*)d_in[1];
    const int*   mpos = (const int*)d_in[2];
    const int*   hts  = (const int*)d_in[3];
    const float* Wh   = (const float*)d_in[4];
    const float* bh   = (const float*)d_in[5];
    const float* Wt   = (const float*)d_in[6];
    const float* bt   = (const float*)d_in[7];
    const float* Wbi  = (const float*)d_in[8];
    const float* bbi  = (const float*)d_in[9];
    float* out = (float*)d_out;

    // workspace layout (f32):  ~36 MB total
    float* ws   = (float*)d_ws;
    float* embs = ws;                                  // B*NE*D     = 129024
    float* eatt = embs + (size_t)Bc * NEc * Dc;        // B*NE*H*L   = 2064384
    float* pw   = eatt + (size_t)Bc * NEc * Hc * Lc;   // B*P*L      = 2097152
    float* rs   = pw   + (size_t)Bc * Pc * Lc;         // B*P*D      = 1572864
    float* zs   = rs   + (size_t)Bc * Pc * Dc;         // B*P*D
    float* zo   = zs   + (size_t)Bc * Pc * Dc;         // B*P*D

    hipMemsetAsync(d_out, 0, (size_t)out_size * sizeof(float), stream);

    k_embs <<<Bc * NEc, 256, 0, stream>>>(seq, mpos, embs);
    k_eatt <<<dim3(Bc * NEc, Hc), 256, 0, stream>>>(att, mpos, eatt);
    k_pairw<<<Bc * Pc, 256, 0, stream>>>(eatt, hts, pw);
    k_rs   <<<dim3(Pc / 64, Dc / 64, Bc), 256, 0, stream>>>(pw, seq, rs);
    k_z    <<<dim3(Bc * Pc / 64, Dc / 64, 2), 256, 0, stream>>>(embs, rs, hts,
                                                                Wh, bh, Wt, bt, zs, zo);
    k_bilin<<<dim3(Bc * Pc / 32, Gc), 256, 0, stream>>>(zs, zo, Wbi, bbi, out);
}

// Round 2
// 590.395 us; speedup vs baseline: 2.9285x; 2.9285x over previous
//
#include <hip/hip_runtime.h>

// Dims (fixed by the problem)
constexpr int Bc  = 4;
constexpr int Lc  = 1024;
constexpr int Dc  = 768;
constexpr int Hc  = 12;
constexpr int NEc = 42;
constexpr int Mc  = 4;
constexpr int Pc  = 512;
constexpr int NLc = 97;
constexpr int NLp = 112;    // padded labels (7 * 16)
constexpr int Gc  = 12;     // D / 64 bilinear groups
constexpr int K2  = 2 * Dc; // 1536
constexpr int KBI = Dc * 64; // 49152

typedef __attribute__((ext_vector_type(8))) short short8;
typedef __attribute__((ext_vector_type(4))) float f32x4;

__device__ __forceinline__ f32x4 mfma16(short8 a, short8 b, f32x4 c) {
    return __builtin_amdgcn_mfma_f32_16x16x32_bf16(a, b, c, 0, 0, 0);
}
__device__ __forceinline__ unsigned short f2bf(float x) {
    unsigned int u = __float_as_uint(x);
    unsigned int r = (u + 0x7fffu + ((u >> 16) & 1u)) >> 16;
    return (unsigned short)r;
}
__device__ __forceinline__ float bf2f(unsigned short h) {
    return __uint_as_float(((unsigned int)h) << 16);
}
__device__ __forceinline__ short8 ld8(const unsigned short* p) {
    return *(const short8*)(const void*)p;
}

// ---------------------------------------------------------------------------
// Kernel A: entity embeddings = logsumexp over M mention tokens -> bf16
__global__ __launch_bounds__(256) void k_embs(const float* __restrict__ seq,
                                              const int* __restrict__ mpos,
                                              unsigned short* __restrict__ embs) {
    int be = blockIdx.x;
    int b  = be / NEc;
    const int* pp = mpos + be * Mc;
    int p0 = pp[0] + 1, p1 = pp[1] + 1, p2 = pp[2] + 1, p3 = pp[3] + 1;
    const float* s = seq + (size_t)b * Lc * Dc;
    for (int d = threadIdx.x; d < Dc; d += 256) {
        float x0 = s[(size_t)p0 * Dc + d];
        float x1 = s[(size_t)p1 * Dc + d];
        float x2 = s[(size_t)p2 * Dc + d];
        float x3 = s[(size_t)p3 * Dc + d];
        float mx = fmaxf(fmaxf(x0, x1), fmaxf(x2, x3));
        float sm = expf(x0 - mx) + expf(x1 - mx) + expf(x2 - mx) + expf(x3 - mx);
        embs[(size_t)be * Dc + d] = f2bf(mx + logf(sm));
    }
}

// ---------------------------------------------------------------------------
// Kernel B: entity attention = mean over M of attn rows -> bf16
__global__ __launch_bounds__(256) void k_eatt(const float* __restrict__ att,
                                              const int* __restrict__ mpos,
                                              unsigned short* __restrict__ eatt) {
    int be = blockIdx.x, h = blockIdx.y;
    int b = be / NEc;
    const int* pp = mpos + be * Mc;
    const float* a  = att + ((size_t)(b * Hc + h)) * Lc * Lc;
    const float* r0 = a + (size_t)(pp[0] + 1) * Lc;
    const float* r1 = a + (size_t)(pp[1] + 1) * Lc;
    const float* r2 = a + (size_t)(pp[2] + 1) * Lc;
    const float* r3 = a + (size_t)(pp[3] + 1) * Lc;
    unsigned short* o = eatt + ((size_t)be * Hc + h) * Lc;
    for (int l = threadIdx.x; l < Lc; l += 256)
        o[l] = f2bf(0.25f * (r0[l] + r1[l] + r2[l] + r3[l]));
}

// ---------------------------------------------------------------------------
// Kernel C: per pair weights w[l] = q[l] / (sum_l q + H*1e-5) -> bf16
__global__ __launch_bounds__(256) void k_pairw(const unsigned short* __restrict__ eatt,
                                               const int* __restrict__ hts,
                                               unsigned short* __restrict__ pw) {
    int bp = blockIdx.x;
    int b  = bp / Pc;
    int hi = hts[bp * 2 + 0], ti = hts[bp * 2 + 1];
    const unsigned short* ai = eatt + ((size_t)(b * NEc + hi)) * Hc * Lc;
    const unsigned short* aj = eatt + ((size_t)(b * NEc + ti)) * Hc * Lc;
    float q[Lc / 256];
    float lsum = 0.f;
    #pragma unroll
    for (int it = 0; it < Lc / 256; ++it) {
        int l = threadIdx.x + it * 256;
        float acc = 0.f;
        #pragma unroll
        for (int h = 0; h < Hc; ++h)
            acc += bf2f(ai[(size_t)h * Lc + l]) * bf2f(aj[(size_t)h * Lc + l]);
        q[it] = acc;
        lsum += acc;
    }
    #pragma unroll
    for (int off = 32; off > 0; off >>= 1)
        lsum += __shfl_down(lsum, off, 64);
    __shared__ float red[4];
    __shared__ float sinv;
    int lane = threadIdx.x & 63, wv = threadIdx.x >> 6;
    if (lane == 0) red[wv] = lsum;
    __syncthreads();
    if (threadIdx.x == 0) {
        float S = red[0] + red[1] + red[2] + red[3];
        sinv = 1.f / (S + 1.2e-4f);   // H * 1e-5
    }
    __syncthreads();
    unsigned short* o = pw + (size_t)bp * Lc;
    #pragma unroll
    for (int it = 0; it < Lc / 256; ++it)
        o[threadIdx.x + it * 256] = f2bf(q[it] * sinv);
}

// ---------------------------------------------------------------------------
// Transpose: seq [B,L,D] f32 -> seq_t [B,D,L] bf16. grid (L/64, D/64, B)
__global__ __launch_bounds__(256) void k_tr_seq(const float* __restrict__ seq,
                                                unsigned short* __restrict__ seq_t) {
    __shared__ float tile[64][65];
    int l0 = blockIdx.x * 64, d0 = blockIdx.y * 64, b = blockIdx.z;
    int tid = threadIdx.x;
    const float* s = seq + (size_t)b * Lc * Dc;
    #pragma unroll
    for (int i = 0; i < 16; ++i) {
        int idx = tid + i * 256;
        int r = idx >> 6, c = idx & 63;
        tile[r][c] = s[(size_t)(l0 + r) * Dc + d0 + c];
    }
    __syncthreads();
    unsigned short* o = seq_t + (size_t)b * Dc * Lc;
    #pragma unroll
    for (int i = 0; i < 16; ++i) {
        int idx = tid + i * 256;
        int r = idx >> 6, c = idx & 63;
        o[(size_t)(d0 + r) * Lc + l0 + c] = f2bf(tile[c][r]);
    }
}

// ---------------------------------------------------------------------------
// Transpose: W [1536,768] f32 -> WT [768,1536] bf16. grid (1536/64, 768/64, 2)
__global__ __launch_bounds__(256) void k_tr_w(const float* __restrict__ Wh,
                                              const float* __restrict__ Wt,
                                              unsigned short* __restrict__ whT,
                                              unsigned short* __restrict__ wtT) {
    __shared__ float tile[64][65];
    int k0 = blockIdx.x * 64, n0 = blockIdx.y * 64;
    const float* W = blockIdx.z ? Wt : Wh;
    unsigned short* WT = blockIdx.z ? wtT : whT;
    int tid = threadIdx.x;
    #pragma unroll
    for (int i = 0; i < 16; ++i) {
        int idx = tid + i * 256;
        int r = idx >> 6, c = idx & 63;
        tile[r][c] = W[(size_t)(k0 + r) * Dc + n0 + c];
    }
    __syncthreads();
    #pragma unroll
    for (int i = 0; i < 16; ++i) {
        int idx = tid + i * 256;
        int r = idx >> 6, c = idx & 63;
        WT[(size_t)(n0 + r) * K2 + k0 + c] = f2bf(tile[c][r]);
    }
}

// ---------------------------------------------------------------------------
// Transpose: W_bi [49152,97] f32 -> wbiT [112,49152] bf16 (zero-padded rows)
// grid 49152/64 = 768 blocks
__global__ __launch_bounds__(256) void k_tr_wbi(const float* __restrict__ wbi,
                                                unsigned short* __restrict__ wbiT) {
    __shared__ float tile[64][NLc];
    int k0 = blockIdx.x * 64;
    int tid = threadIdx.x;
    for (int idx = tid; idx < 64 * NLc; idx += 256) {
        int r = idx / NLc, c = idx - r * NLc;
        tile[r][c] = wbi[(size_t)(k0 + r) * NLc + c];
    }
    __syncthreads();
    for (int idx = tid; idx < NLp * 64; idx += 256) {
        int n = idx >> 6, c = idx & 63;
        float v = (n < NLc) ? tile[c][n] : 0.0f;
        wbiT[(size_t)n * KBI + k0 + c] = f2bf(v);
    }
}

// ---------------------------------------------------------------------------
// Kernel D (MFMA): rs[bp,d] = sum_l pw[bp,l]*seq[b,l,d] -> bf16
// grid (512/64, 768/64, B); 4 waves, each wave: M=16 x N=64
__global__ __launch_bounds__(256) void k_rs(const unsigned short* __restrict__ pw,
                                            const unsigned short* __restrict__ seq_t,
                                            unsigned short* __restrict__ rs) {
    int tid = threadIdx.x, wave = tid >> 6, lane = tid & 63;
    int quad = lane >> 4, lm = lane & 15;
    int b = blockIdx.z;
    int p0 = blockIdx.x * 64 + wave * 16;
    int n0 = blockIdx.y * 64;
    const unsigned short* arow = pw + ((size_t)(b * Pc + p0 + lm)) * Lc + quad * 8;
    const unsigned short* brow[4];
    #pragma unroll
    for (int f = 0; f < 4; ++f)
        brow[f] = seq_t + ((size_t)(b * Dc + n0 + f * 16 + lm)) * Lc + quad * 8;
    f32x4 acc[4] = {};
    #pragma unroll 4
    for (int k0 = 0; k0 < Lc; k0 += 32) {
        short8 a = ld8(arow + k0);
        #pragma unroll
        for (int f = 0; f < 4; ++f)
            acc[f] = mfma16(a, ld8(brow[f] + k0), acc[f]);
    }
    #pragma unroll
    for (int f = 0; f < 4; ++f) {
        int col = n0 + f * 16 + lm;
        #pragma unroll
        for (int r = 0; r < 4; ++r) {
            int bp = b * Pc + p0 + quad * 4 + r;
            rs[(size_t)bp * Dc + col] = f2bf(acc[f][r]);
        }
    }
}

// ---------------------------------------------------------------------------
// Kernel E (MFMA): z = tanh([emb, rs] @ W + b) -> bf16
// grid (2048/64, 768/64, 2); 4 waves, each: M=16 x N=64, K=1536
__global__ __launch_bounds__(256) void k_z(const unsigned short* __restrict__ embs,
                                           const unsigned short* __restrict__ rs,
                                           const int* __restrict__ hts,
                                           const unsigned short* __restrict__ whT,
                                           const unsigned short* __restrict__ wtT,
                                           const float* __restrict__ bh,
                                           const float* __restrict__ bt,
                                           unsigned short* __restrict__ zs,
                                           unsigned short* __restrict__ zo) {
    int tid = threadIdx.x, wave = tid >> 6, lane = tid & 63;
    int quad = lane >> 4, lm = lane & 15;
    int which = blockIdx.z;
    int m0 = blockIdx.x * 64 + wave * 16;
    int n0 = blockIdx.y * 64;
    int row = m0 + lm;
    int b = row >> 9;
    int e = hts[row * 2 + which];
    const unsigned short* a1 = embs + ((size_t)(b * NEc + e)) * Dc + quad * 8;
    const unsigned short* a2 = rs + (size_t)row * Dc + quad * 8;
    const unsigned short* WT = which ? wtT : whT;
    const float* bias = which ? bt : bh;
    unsigned short* outp = which ? zo : zs;
    const unsigned short* brow[4];
    #pragma unroll
    for (int f = 0; f < 4; ++f)
        brow[f] = WT + ((size_t)(n0 + f * 16 + lm)) * K2 + quad * 8;
    f32x4 acc[4] = {};
    #pragma unroll 4
    for (int k0 = 0; k0 < Dc; k0 += 32) {
        short8 a = ld8(a1 + k0);
        #pragma unroll
        for (int f = 0; f < 4; ++f)
            acc[f] = mfma16(a, ld8(brow[f] + k0), acc[f]);
    }
    #pragma unroll 4
    for (int k0 = 0; k0 < Dc; k0 += 32) {
        short8 a = ld8(a2 + k0);
        #pragma unroll
        for (int f = 0; f < 4; ++f)
            acc[f] = mfma16(a, ld8(brow[f] + Dc + k0), acc[f]);
    }
    #pragma unroll
    for (int f = 0; f < 4; ++f) {
        int col = n0 + f * 16 + lm;
        float bv = bias[col];
        #pragma unroll
        for (int r = 0; r < 4; ++r) {
            int orow = m0 + quad * 4 + r;
            outp[(size_t)orow * Dc + col] = f2bf(tanhf(acc[f][r] + bv));
        }
    }
}

// ---------------------------------------------------------------------------
// Kernel F (MFMA): grouped bilinear via rank-1 trick.
// out[p,n] += sum_x zs[p,gx] * (sum_y zo[p,gy]*W[g,x,y,n])
// grid (2048/64, 7, 12); 4 waves, each: M=16 x N=16, one group
__global__ __launch_bounds__(256) void k_bilin(const unsigned short* __restrict__ zs,
                                               const unsigned short* __restrict__ zo,
                                               const unsigned short* __restrict__ wbiT,
                                               const float* __restrict__ bbi,
                                               float* __restrict__ out) {
    int tid = threadIdx.x, wave = tid >> 6, lane = tid & 63;
    int quad = lane >> 4, lm = lane & 15;
    int m0 = blockIdx.x * 64 + wave * 16;
    int n0 = blockIdx.y * 16;
    int g  = blockIdx.z;
    // zo A-frags (reused across all 64 x of the group)
    const unsigned short* zorow = zo + (size_t)(m0 + lm) * Dc + g * 64;
    short8 a0 = ld8(zorow + quad * 8);
    short8 a1 = ld8(zorow + 32 + quad * 8);
    // zs row bases for this lane's 4 output rows
    const unsigned short* zsb[4];
    #pragma unroll
    for (int i = 0; i < 4; ++i)
        zsb[i] = zs + (size_t)(m0 + quad * 4 + i) * Dc + g * 64;
    const unsigned short* wrow = wbiT + (size_t)(n0 + lm) * KBI + g * 4096 + quad * 8;
    f32x4 acc = {0.f, 0.f, 0.f, 0.f};
    const f32x4 zero = {0.f, 0.f, 0.f, 0.f};
    for (int xb = 0; xb < 8; ++xb) {
        short8 s8[4];
        #pragma unroll
        for (int i = 0; i < 4; ++i)
            s8[i] = ld8(zsb[i] + xb * 8);
        #pragma unroll
        for (int j = 0; j < 8; ++j) {
            int x = xb * 8 + j;
            short8 b0 = ld8(wrow + x * 64);
            short8 b1 = ld8(wrow + x * 64 + 32);
            f32x4 t = mfma16(a0, b0, zero);
            t = mfma16(a1, b1, t);
            #pragma unroll
            for (int i = 0; i < 4; ++i)
                acc[i] += bf2f((unsigned short)s8[i][j]) * t[i];
        }
    }
    int n = n0 + lm;
    if (n < NLc) {
        #pragma unroll
        for (int i = 0; i < 4; ++i) {
            int row = m0 + quad * 4 + i;
            float v = acc[i];
            if (g == 0) v += bbi[n];
            atomicAdd(out + (size_t)row * NLc + n, v);
        }
    }
}

// ---------------------------------------------------------------------------
extern "C" void kernel_launch(void* const* d_in, const int* in_sizes, int n_in,
                              void* d_out, int out_size, void* d_ws, size_t ws_size,
                              hipStream_t stream) {
    const float* seq  = (const float*)d_in[0];
    const float* att  = (const float*)d_in[1];
    const int*   mpos = (const int*)d_in[2];
    const int*   hts  = (const int*)d_in[3];
    const float* Wh   = (const float*)d_in[4];
    const float* bh   = (const float*)d_in[5];
    const float* Wt   = (const float*)d_in[6];
    const float* bt   = (const float*)d_in[7];
    const float* Wbi  = (const float*)d_in[8];
    const float* bbi  = (const float*)d_in[9];
    float* out = (float*)d_out;

    // Workspace layout (bytes). wbiT overlays [eatt|pw|seq_t] (dead after k_rs).
    char* w = (char*)d_ws;
    unsigned short* embs_bf = (unsigned short*)(w);                    // 258,048
    unsigned short* eatt_bf = (unsigned short*)(w + 258048);           // 4,128,768
    unsigned short* pw_bf   = (unsigned short*)(w + 258048 + 4128768); // 4,194,304
    unsigned short* seq_t   = (unsigned short*)(w + 258048 + 4128768 + 4194304); // 6,291,456
    unsigned short* wbiT    = eatt_bf;                                 // 11,010,048 (fits in 14,614,528)
    size_t off = 258048 + 4128768 + 4194304 + 6291456;                 // 14,872,576
    unsigned short* whT   = (unsigned short*)(w + off);                // 2,359,296
    unsigned short* wtT   = (unsigned short*)(w + off + 2359296);      // 2,359,296
    unsigned short* rs_bf = (unsigned short*)(w + off + 2 * 2359296);  // 3,145,728
    unsigned short* zs_bf = (unsigned short*)(w + off + 2 * 2359296 + 3145728);
    unsigned short* zo_bf = (unsigned short*)(w + off + 2 * 2359296 + 2 * 3145728);
    // total = 27,673,600 bytes

    hipMemsetAsync(d_out, 0, (size_t)out_size * sizeof(float), stream);

    k_embs  <<<Bc * NEc, 256, 0, stream>>>(seq, mpos, embs_bf);
    k_eatt  <<<dim3(Bc * NEc, Hc), 256, 0, stream>>>(att, mpos, eatt_bf);
    k_pairw <<<Bc * Pc, 256, 0, stream>>>(eatt_bf, hts, pw_bf);
    k_tr_seq<<<dim3(Lc / 64, Dc / 64, Bc), 256, 0, stream>>>(seq, seq_t);
    k_tr_w  <<<dim3(K2 / 64, Dc / 64, 2), 256, 0, stream>>>(Wh, Wt, whT, wtT);
    k_rs    <<<dim3(Pc / 64, Dc / 64, Bc), 256, 0, stream>>>(pw_bf, seq_t, rs_bf);
    // wbiT overlays eatt/pw/seq_t -- must launch after k_rs
    k_tr_wbi<<<KBI / 64, 256, 0, stream>>>(Wbi, wbiT);
    k_z     <<<dim3(Bc * Pc / 64, Dc / 64, 2), 256, 0, stream>>>(embs_bf, rs_bf, hts,
                                                                 whT, wtT, bh, bt, zs_bf, zo_bf);
    k_bilin <<<dim3(Bc * Pc / 64, NLp / 16, Gc), 256, 0, stream>>>(zs_bf, zo_bf, wbiT, bbi, out);
}

// Round 4
// 387.643 us; speedup vs baseline: 4.4601x; 1.5230x over previous
//
#include <hip/hip_runtime.h>

constexpr int Bc = 4, Lc = 1024, Dc = 768, Hc = 12, NEc = 42, Mc = 4, Pc = 512, NLc = 97;
constexpr int BE   = Bc * NEc;   // 168 entities
constexpr int BEp  = 176;        // padded to 11 m-tiles
constexpr int ROWS = Bc * Pc;    // 2048 pairs
constexpr int N2   = 2 * Dc;     // 1536

typedef __attribute__((ext_vector_type(8))) short short8;
typedef _Float16 half8 __attribute__((ext_vector_type(8)));
typedef __attribute__((ext_vector_type(4))) float f32x4;

__device__ __forceinline__ f32x4 mfma_bf(short8 a, short8 b, f32x4 c) {
    return __builtin_amdgcn_mfma_f32_16x16x32_bf16(a, b, c, 0, 0, 0);
}
__device__ __forceinline__ f32x4 mfma_h(half8 a, half8 b, f32x4 c) {
    return __builtin_amdgcn_mfma_f32_16x16x32_f16(a, b, c, 0, 0, 0);
}
__device__ __forceinline__ unsigned short f2bf(float x) {
    unsigned int u = __float_as_uint(x);
    return (unsigned short)((u + 0x7fffu + ((u >> 16) & 1u)) >> 16);
}
__device__ __forceinline__ float bf2f(unsigned short h) {
    return __uint_as_float(((unsigned int)h) << 16);
}
__device__ __forceinline__ short8 ld8(const unsigned short* p) {
    return *(const short8*)(const void*)p;
}
__device__ __forceinline__ half8 ldh8(const _Float16* p) {
    return *(const half8*)(const void*)p;
}

// A/B-pack layout (16x16x32 fragments): idx = ((tile*NKB + kb)*512) + lane*8 + j
// where lane = ((k>>3)&3)*16 + (row_or_col & 15), j = k & 7, kb = k >> 5.

// ---------------------------------------------------------------------------
// entity logsumexp embeds -> A-pack [11 mt][24 kb], rows >= 168 zeroed
__global__ __launch_bounds__(256) void k_embs(const float* __restrict__ seq,
                                              const int* __restrict__ mpos,
                                              unsigned short* __restrict__ ep) {
    int be = blockIdx.x, mt = be >> 4, lm = be & 15;
    float vals[3] = {0.f, 0.f, 0.f};
    if (be < BE) {
        int b = be / NEc;
        const int* pp = mpos + be * Mc;
        int p0 = pp[0] + 1, p1 = pp[1] + 1, p2 = pp[2] + 1, p3 = pp[3] + 1;
        const float* s = seq + (size_t)b * Lc * Dc;
        #pragma unroll
        for (int i = 0; i < 3; ++i) {
            int d = threadIdx.x + i * 256;
            float x0 = s[(size_t)p0 * Dc + d], x1 = s[(size_t)p1 * Dc + d];
            float x2 = s[(size_t)p2 * Dc + d], x3 = s[(size_t)p3 * Dc + d];
            float mx = fmaxf(fmaxf(x0, x1), fmaxf(x2, x3));
            vals[i] = mx + logf(expf(x0 - mx) + expf(x1 - mx) + expf(x2 - mx) + expf(x3 - mx));
        }
    }
    #pragma unroll
    for (int i = 0; i < 3; ++i) {
        int d = threadIdx.x + i * 256;
        int idx = ((mt * 24 + (d >> 5)) << 9) + (((d >> 3) & 3) << 7) + (lm << 3) + (d & 7);
        ep[idx] = f2bf(vals[i]);
    }
}

// ---------------------------------------------------------------------------
// entity attention mean -> bf16 [be][h][l]
__global__ __launch_bounds__(256) void k_eatt(const float* __restrict__ att,
                                              const int* __restrict__ mpos,
                                              unsigned short* __restrict__ eatt) {
    int be = blockIdx.x, h = blockIdx.y, b = be / NEc;
    const int* pp = mpos + be * Mc;
    const float* a = att + ((size_t)(b * Hc + h)) * Lc * Lc;
    const float4* r0 = (const float4*)(a + (size_t)(pp[0] + 1) * Lc);
    const float4* r1 = (const float4*)(a + (size_t)(pp[1] + 1) * Lc);
    const float4* r2 = (const float4*)(a + (size_t)(pp[2] + 1) * Lc);
    const float4* r3 = (const float4*)(a + (size_t)(pp[3] + 1) * Lc);
    unsigned short* o = eatt + ((size_t)be * Hc + h) * Lc;
    int t = threadIdx.x;
    float4 v0 = r0[t], v1 = r1[t], v2 = r2[t], v3 = r3[t];
    o[t * 4 + 0] = f2bf(0.25f * (v0.x + v1.x + v2.x + v3.x));
    o[t * 4 + 1] = f2bf(0.25f * (v0.y + v1.y + v2.y + v3.y));
    o[t * 4 + 2] = f2bf(0.25f * (v0.z + v1.z + v2.z + v3.z));
    o[t * 4 + 3] = f2bf(0.25f * (v0.w + v1.w + v2.w + v3.w));
}

// ---------------------------------------------------------------------------
// pair weights -> A-pack [128 mt][32 kb]
__global__ __launch_bounds__(256) void k_pairw(const unsigned short* __restrict__ eatt,
                                               const int* __restrict__ hts,
                                               unsigned short* __restrict__ pwp) {
    int bp = blockIdx.x, b = bp / Pc;
    int hi = hts[bp * 2], ti = hts[bp * 2 + 1];
    const unsigned short* ai = eatt + ((size_t)(b * NEc + hi)) * Hc * Lc;
    const unsigned short* aj = eatt + ((size_t)(b * NEc + ti)) * Hc * Lc;
    int l0 = threadIdx.x * 4;
    float acc[4] = {0.f, 0.f, 0.f, 0.f};
    #pragma unroll
    for (int h = 0; h < Hc; ++h) {
        uint2 ua = *(const uint2*)(ai + h * Lc + l0);
        uint2 ub = *(const uint2*)(aj + h * Lc + l0);
        acc[0] += bf2f(ua.x & 0xffff) * bf2f(ub.x & 0xffff);
        acc[1] += bf2f(ua.x >> 16)    * bf2f(ub.x >> 16);
        acc[2] += bf2f(ua.y & 0xffff) * bf2f(ub.y & 0xffff);
        acc[3] += bf2f(ua.y >> 16)    * bf2f(ub.y >> 16);
    }
    float lsum = acc[0] + acc[1] + acc[2] + acc[3];
    #pragma unroll
    for (int off = 32; off > 0; off >>= 1) lsum += __shfl_down(lsum, off, 64);
    __shared__ float red[4];
    __shared__ float sinv;
    int lane = threadIdx.x & 63, wv = threadIdx.x >> 6;
    if (lane == 0) red[wv] = lsum;
    __syncthreads();
    if (threadIdx.x == 0) sinv = 1.f / (red[0] + red[1] + red[2] + red[3] + 1.2e-4f);
    __syncthreads();
    float s = sinv;
    unsigned short w0 = f2bf(acc[0] * s), w1 = f2bf(acc[1] * s);
    unsigned short w2 = f2bf(acc[2] * s), w3 = f2bf(acc[3] * s);
    int mt = bp >> 4, lm = bp & 15, kb = l0 >> 5, quad = (l0 >> 3) & 3, j0 = l0 & 7;
    unsigned short* dst = pwp + ((mt * 32 + kb) << 9) + (quad << 7) + (lm << 3) + j0;
    *(uint2*)dst = make_uint2((unsigned)w0 | ((unsigned)w1 << 16),
                              (unsigned)w2 | ((unsigned)w3 << 16));
}

// ---------------------------------------------------------------------------
// seq [B,L,D] f32 -> B-pack [b][48 nt][32 kb] bf16 (n=d, k=l)
__global__ __launch_bounds__(256) void k_tr_seq(const float* __restrict__ seq,
                                                unsigned short* __restrict__ sp) {
    __shared__ float tile[64][65];
    int l0 = blockIdx.x * 64, d0 = blockIdx.y * 64, b = blockIdx.z;
    int t = threadIdx.x;
    const float* s = seq + (size_t)b * Lc * Dc;
    #pragma unroll
    for (int i = 0; i < 16; ++i) {
        int idx = t + i * 256, r = idx >> 6, c = idx & 63;
        tile[r][c] = s[(size_t)(l0 + r) * Dc + d0 + c];
    }
    __syncthreads();
    unsigned short* outb = sp + (size_t)b * 48 * 32 * 512;
    int flat = t * 2, lane = flat >> 3, j = flat & 7;
    #pragma unroll
    for (int nt_i = 0; nt_i < 4; ++nt_i)
        #pragma unroll
        for (int kb_i = 0; kb_i < 2; ++kb_i) {
            int kl = kb_i * 32 + (lane >> 4) * 8 + j;
            int c  = nt_i * 16 + (lane & 15);
            unsigned int v = (unsigned)f2bf(tile[kl][c]) | ((unsigned)f2bf(tile[kl + 1][c]) << 16);
            *(unsigned int*)&outb[(((d0 / 16 + nt_i) * 32 + (l0 / 32 + kb_i)) << 9) + flat] = v;
        }
}

// ---------------------------------------------------------------------------
// Wh/Wt [1536][768] f32 -> Wp1 (k 0:768), Wp2 (k 768:1536), B-pack [96 nt][24 kb]
// n' = which*768 + n
__global__ __launch_bounds__(256) void k_tr_w(const float* __restrict__ Wh,
                                              const float* __restrict__ Wt,
                                              unsigned short* __restrict__ wp1,
                                              unsigned short* __restrict__ wp2) {
    __shared__ float tile[64][65];
    int k0 = blockIdx.x * 64, n0 = blockIdx.y * 64, which = blockIdx.z;
    const float* W = which ? Wt : Wh;
    int t = threadIdx.x;
    #pragma unroll
    for (int i = 0; i < 16; ++i) {
        int idx = t + i * 256, r = idx >> 6, c = idx & 63;
        tile[r][c] = W[(size_t)(k0 + r) * Dc + n0 + c];
    }
    __syncthreads();
    unsigned short* dst = (k0 < Dc) ? wp1 : wp2;
    int kb0 = ((k0 < Dc) ? k0 : (k0 - Dc)) / 32;
    int nt0 = which * 48 + n0 / 16;
    int flat = t * 2, lane = flat >> 3, j = flat & 7;
    #pragma unroll
    for (int nt_i = 0; nt_i < 4; ++nt_i)
        #pragma unroll
        for (int kb_i = 0; kb_i < 2; ++kb_i) {
            int kl = kb_i * 32 + (lane >> 4) * 8 + j;
            int c  = nt_i * 16 + (lane & 15);
            unsigned int v = (unsigned)f2bf(tile[kl][c]) | ((unsigned)f2bf(tile[kl + 1][c]) << 16);
            *(unsigned int*)&dst[(((nt0 + nt_i) * 24 + kb0 + kb_i) << 9) + flat] = v;
        }
}

// ---------------------------------------------------------------------------
// W_bi [49152,97] f32 -> f16 B-pack [(nt*12+g)*64 + x][2 half][64 lane][8], n pad->0
__global__ __launch_bounds__(256) void k_tr_wbi(const float* __restrict__ wbi,
                                                _Float16* __restrict__ wbp) {
    __shared__ float lds[64 * 97];
    int x = blockIdx.x, g = blockIdx.y;
    const float* src = wbi + (size_t)(g * 4096 + x * 64) * NLc;
    for (int i = threadIdx.x; i < 64 * NLc; i += 256) lds[i] = src[i];
    __syncthreads();
    int flat = threadIdx.x * 2, lane = flat >> 3, j = flat & 7;
    int lm = lane & 15, qj = (lane >> 4) * 8 + j;
    #pragma unroll
    for (int nt = 0; nt < 7; ++nt)
        #pragma unroll
        for (int half = 0; half < 2; ++half) {
            int y = half * 32 + qj;
            int n = nt * 16 + lm;
            _Float16 v0 = (n < NLc) ? (_Float16)lds[y * NLc + n] : (_Float16)0.f;
            _Float16 v1 = (n < NLc) ? (_Float16)lds[(y + 1) * NLc + n] : (_Float16)0.f;
            size_t base = ((((size_t)(nt * 12 + g) * 64 + x) * 2 + half) << 9);
            _Float16* d = wbp + base + flat;
            d[0] = v0; d[1] = v1;
        }
}

// ---------------------------------------------------------------------------
// rs = pw @ seq -> A-pack [128 mt][24 kb] bf16.  grid (8 mb, 12 ntq, 4 b), 4 waves
__global__ __launch_bounds__(256) void k_rs(const unsigned short* __restrict__ pwp,
                                            const unsigned short* __restrict__ sp,
                                            unsigned short* __restrict__ rsp) {
    int tid = threadIdx.x, wave = tid >> 6, lane = tid & 63;
    int quad = lane >> 4, lm = lane & 15;
    int nt = blockIdx.y * 4 + wave, b = blockIdx.z, mb = blockIdx.x;
    int mt0 = b * 32 + mb * 4;
    const unsigned short* bbase = sp + (((size_t)b * 48 + nt) * 32 << 9) + lane * 8;
    const unsigned short* abase = pwp + ((size_t)mt0 * 32 << 9) + lane * 8;
    f32x4 acc[4] = {};
    for (int kb = 0; kb < 32; ++kb) {
        short8 bf = ld8(bbase + kb * 512);
        #pragma unroll
        for (int mf = 0; mf < 4; ++mf)
            acc[mf] = mfma_bf(ld8(abase + (mf * 32 + kb) * 512), bf, acc[mf]);
    }
    int n = nt * 16 + lm, kbo = n >> 5, lq = ((n >> 3) & 3) << 4, jo = n & 7;
    #pragma unroll
    for (int mf = 0; mf < 4; ++mf) {
        unsigned short* db = rsp + (((mt0 + mf) * 24 + kbo) << 9) + jo;
        #pragma unroll
        for (int r = 0; r < 4; ++r)
            db[(lq + quad * 4 + r) << 3] = f2bf(acc[mf][r]);
    }
}

// ---------------------------------------------------------------------------
// E[be][n'] = emb[be] @ [Wh1 | Wt1] -> bf16 [176][1536].  grid (11 mt, 24 ntq)
__global__ __launch_bounds__(256) void k_E(const unsigned short* __restrict__ ep,
                                           const unsigned short* __restrict__ wp1,
                                           unsigned short* __restrict__ E) {
    int tid = threadIdx.x, wave = tid >> 6, lane = tid & 63;
    int quad = lane >> 4, lm = lane & 15;
    int mt = blockIdx.x, nt = blockIdx.y * 4 + wave;
    const unsigned short* ab = ep + (mt * 24 << 9) + lane * 8;
    const unsigned short* bb = wp1 + (nt * 24 << 9) + lane * 8;
    f32x4 acc = {};
    for (int kb = 0; kb < 24; ++kb)
        acc = mfma_bf(ld8(ab + kb * 512), ld8(bb + kb * 512), acc);
    #pragma unroll
    for (int r = 0; r < 4; ++r)
        E[(size_t)(mt * 16 + quad * 4 + r) * N2 + nt * 16 + lm] = f2bf(acc[r]);
}

// ---------------------------------------------------------------------------
// R[row][n'] = rs[row] @ [Wh2 | Wt2] -> bf16 [2048][1536].  grid (32 mb, 24 ntq)
__global__ __launch_bounds__(256) void k_R(const unsigned short* __restrict__ rsp,
                                           const unsigned short* __restrict__ wp2,
                                           unsigned short* __restrict__ R) {
    int tid = threadIdx.x, wave = tid >> 6, lane = tid & 63;
    int quad = lane >> 4, lm = lane & 15;
    int mt0 = blockIdx.x * 4, nt = blockIdx.y * 4 + wave;
    const unsigned short* bb = wp2 + (nt * 24 << 9) + lane * 8;
    const unsigned short* ab = rsp + ((size_t)mt0 * 24 << 9) + lane * 8;
    f32x4 acc[4] = {};
    for (int kb = 0; kb < 24; ++kb) {
        short8 bf = ld8(bb + kb * 512);
        #pragma unroll
        for (int mf = 0; mf < 4; ++mf)
            acc[mf] = mfma_bf(ld8(ab + (mf * 24 + kb) * 512), bf, acc[mf]);
    }
    #pragma unroll
    for (int mf = 0; mf < 4; ++mf)
        #pragma unroll
        for (int r = 0; r < 4; ++r)
            R[(size_t)((mt0 + mf) * 16 + quad * 4 + r) * N2 + nt * 16 + lm] = f2bf(acc[mf][r]);
}

// ---------------------------------------------------------------------------
// zs = tanh(E_h + R_h + bh) -> f16 row-major; zo = tanh(E_t + R_t + bt) -> f16 A-pack
__global__ __launch_bounds__(256) void k_zfin(const unsigned short* __restrict__ E,
                                              const unsigned short* __restrict__ R,
                                              const int* __restrict__ hts,
                                              const float* __restrict__ bh,
                                              const float* __restrict__ bt,
                                              _Float16* __restrict__ zs,
                                              _Float16* __restrict__ zop) {
    int row = blockIdx.x, b = row >> 9;
    int hh = hts[row * 2], tt = hts[row * 2 + 1];
    const unsigned short* Eh = E + (size_t)(b * NEc + hh) * N2;
    const unsigned short* Et = E + (size_t)(b * NEc + tt) * N2 + Dc;
    const unsigned short* Rr = R + (size_t)row * N2;
    #pragma unroll
    for (int i = 0; i < 3; ++i) {
        int n = threadIdx.x + i * 256;
        float vs = tanhf(bf2f(Eh[n]) + bf2f(Rr[n]) + bh[n]);
        float vo = tanhf(bf2f(Et[n]) + bf2f(Rr[Dc + n]) + bt[n]);
        zs[(size_t)row * Dc + n] = (_Float16)vs;
        int idx = (((row >> 4) * 24 + (n >> 5)) << 9) + (((((n >> 3) & 3) << 4) + (row & 15)) << 3) + (n & 7);
        zop[idx] = (_Float16)vo;
    }
}

// ---------------------------------------------------------------------------
// grouped bilinear: out[row,n] += sum_{x,y} zs[row,gx] zo[row,gy] W[g,x,y,n]
// grid (8 pb, 7 nt, 12 g), 4 waves; wave: M=64, N=16, K=g's 4096 (zs folded into A in f16)
__global__ __launch_bounds__(256) void k_bilin(const _Float16* __restrict__ zs,
                                               const _Float16* __restrict__ zop,
                                               const _Float16* __restrict__ wbp,
                                               const float* __restrict__ bbi,
                                               float* __restrict__ out) {
    __shared__ _Float16 zlds[256 * 72];
    int tid = threadIdx.x, wave = tid >> 6, lane = tid & 63;
    int quad = lane >> 4, lm = lane & 15;
    int pb = blockIdx.x, nt = blockIdx.y, g = blockIdx.z;
    {
        const half8* src = (const half8*)(zs + ((size_t)(pb * 256 + tid)) * Dc + g * 64);
        half8* dst = (half8*)&zlds[tid * 72];
        #pragma unroll
        for (int c = 0; c < 8; ++c) dst[c] = src[c];   // 64 halves = full group slice
    }
    __syncthreads();
    int mt0 = pb * 16 + wave * 4;
    half8 zofr[4][2];
    #pragma unroll
    for (int mf = 0; mf < 4; ++mf)
        #pragma unroll
        for (int hf = 0; hf < 2; ++hf)
            zofr[mf][hf] = ldh8(zop + (((mt0 + mf) * 24 + g * 2 + hf) << 9) + lane * 8);
    const _Float16* wbase = wbp + ((size_t)(nt * 12 + g) << 16) + lane * 8;
    const _Float16* zrow = &zlds[(wave * 64 + lm) * 72];
    f32x4 acc[4] = {};
    for (int x = 0; x < 64; ++x) {
        half8 b0 = ldh8(wbase + x * 1024);
        half8 b1 = ldh8(wbase + x * 1024 + 512);
        #pragma unroll
        for (int mf = 0; mf < 4; ++mf) {
            _Float16 s = zrow[mf * 16 * 72 + x];
            half8 bc = {s, s, s, s, s, s, s, s};
            acc[mf] = mfma_h(bc * zofr[mf][0], b0, acc[mf]);
            acc[mf] = mfma_h(bc * zofr[mf][1], b1, acc[mf]);
        }
    }
    int n = nt * 16 + lm;
    if (n < NLc) {
        #pragma unroll
        for (int mf = 0; mf < 4; ++mf)
            #pragma unroll
            for (int r = 0; r < 4; ++r) {
                int row = (mt0 + mf) * 16 + quad * 4 + r;
                float v = acc[mf][r];
                if (g == 0) v += bbi[n];
                atomicAdd(out + (size_t)row * NLc + n, v);
            }
    }
}

// ---------------------------------------------------------------------------
extern "C" void kernel_launch(void* const* d_in, const int* in_sizes, int n_in,
                              void* d_out, int out_size, void* d_ws, size_t ws_size,
                              hipStream_t stream) {
    const float* seq  = (const float*)d_in[0];
    const float* att  = (const float*)d_in[1];
    const int*   mpos = (const int*)d_in[2];
    const int*   hts  = (const int*)d_in[3];
    const float* Wh   = (const float*)d_in[4];
    const float* bh   = (const float*)d_in[5];
    const float* Wt   = (const float*)d_in[6];
    const float* bt   = (const float*)d_in[7];
    const float* Wbi  = (const float*)d_in[8];
    const float* bbi  = (const float*)d_in[9];
    float* out = (float*)d_out;

    // Workspace layout. Region 1 (embs_pack|eatt|pw_pack|seq_pack, 14,884,864 B)
    // is overlaid by wbi_pack (11,010,048 B) once k_E/k_pairw/k_rs are done.
    char* w = (char*)d_ws;
    unsigned short* embs_p = (unsigned short*)(w);                 //   270,336
    unsigned short* eatt_b = (unsigned short*)(w + 270336);        // 4,128,768
    unsigned short* pw_p   = (unsigned short*)(w + 4399104);       // 4,194,304
    unsigned short* seq_p  = (unsigned short*)(w + 8593408);       // 6,291,456
    _Float16*       wbi_p  = (_Float16*)(w);                       // overlay: 11,010,048
    unsigned short* wp1    = (unsigned short*)(w + 14884864);      // 2,359,296
    unsigned short* wp2    = (unsigned short*)(w + 17244160);      // 2,359,296
    unsigned short* E      = (unsigned short*)(w + 19603456);      //   540,672
    unsigned short* rs_p   = (unsigned short*)(w + 20144128);      // 3,145,728
    unsigned short* R      = (unsigned short*)(w + 23289856);      // 6,291,456
    _Float16*       zs     = (_Float16*)(w + 29581312);            // 3,145,728
    _Float16*       zo_p   = (_Float16*)(w + 32727040);            // 3,145,728
    // total 35,872,768 B

    hipMemsetAsync(d_out, 0, (size_t)out_size * sizeof(float), stream);

    k_embs  <<<BEp, 256, 0, stream>>>(seq, mpos, embs_p);
    k_eatt  <<<dim3(BE, Hc), 256, 0, stream>>>(att, mpos, eatt_b);
    k_pairw <<<ROWS, 256, 0, stream>>>(eatt_b, hts, pw_p);
    k_tr_seq<<<dim3(16, 12, 4), 256, 0, stream>>>(seq, seq_p);
    k_tr_w  <<<dim3(24, 12, 2), 256, 0, stream>>>(Wh, Wt, wp1, wp2);
    k_rs    <<<dim3(8, 12, 4), 256, 0, stream>>>(pw_p, seq_p, rs_p);
    k_E     <<<dim3(11, 24), 256, 0, stream>>>(embs_p, wp1, E);
    // overlay write: only after k_pairw (eatt), k_rs (pw,seq), k_E (embs) are done
    k_tr_wbi<<<dim3(64, 12), 256, 0, stream>>>(Wbi, wbi_p);
    k_R     <<<dim3(32, 24), 256, 0, stream>>>(rs_p, wp2, R);
    k_zfin  <<<ROWS, 256, 0, stream>>>(E, R, hts, bh, bt, zs, zo_p);
    k_bilin <<<dim3(8, 7, 12), 256, 0, stream>>>(zs, zo_p, wbi_p, bbi, out);
}

// Round 5
// 371.790 us; speedup vs baseline: 4.6503x; 1.0426x over previous
//
#include <hip/hip_runtime.h>

constexpr int Bc = 4, Lc = 1024, Dc = 768, Hc = 12, NEc = 42, Mc = 4, Pc = 512, NLc = 97;
constexpr int BE   = Bc * NEc;   // 168 entities
constexpr int BEp  = 176;        // padded to 11 m-tiles
constexpr int ROWS = Bc * Pc;    // 2048 pairs
constexpr int N2   = 2 * Dc;     // 1536

typedef __attribute__((ext_vector_type(8))) short short8;
typedef _Float16 half8 __attribute__((ext_vector_type(8)));
typedef __attribute__((ext_vector_type(4))) float f32x4;

__device__ __forceinline__ f32x4 mfma_bf(short8 a, short8 b, f32x4 c) {
    return __builtin_amdgcn_mfma_f32_16x16x32_bf16(a, b, c, 0, 0, 0);
}
__device__ __forceinline__ f32x4 mfma_h(half8 a, half8 b, f32x4 c) {
    return __builtin_amdgcn_mfma_f32_16x16x32_f16(a, b, c, 0, 0, 0);
}
__device__ __forceinline__ unsigned short f2bf(float x) {
    unsigned int u = __float_as_uint(x);
    return (unsigned short)((u + 0x7fffu + ((u >> 16) & 1u)) >> 16);
}
__device__ __forceinline__ float bf2f(unsigned short h) {
    return __uint_as_float(((unsigned int)h) << 16);
}
__device__ __forceinline__ short8 ld8(const unsigned short* p) {
    return *(const short8*)(const void*)p;
}
__device__ __forceinline__ half8 ldh8(const _Float16* p) {
    return *(const half8*)(const void*)p;
}

// A/B-pack layout (16x16x32 fragments): idx = ((tile*NKB + kb)*512) + lane*8 + j
// where lane = ((k>>3)&3)*16 + (row_or_col & 15), j = k & 7, kb = k >> 5.

// Fused-prep block ranges
constexpr int PB_EMBS  = 0;                    // 176
constexpr int PB_EATT  = PB_EMBS + BEp;        // +2016 = 2192
constexpr int PB_TRSEQ = PB_EATT + BE * Hc;    // +768  = 2960
constexpr int PB_TRW   = PB_TRSEQ + 768;       // +576  = 3536
constexpr int PB_TRWBI = PB_TRW + 576;         // +768  = 4304
constexpr int PB_ZERO  = PB_TRWBI + 768;       // +97   = 4401
constexpr int PB_TOTAL = PB_ZERO + 97;

// ---------------------------------------------------------------------------
// k_prep: all independent preprocessing in ONE dispatch (branch by block range)
__global__ __launch_bounds__(256) void k_prep(const float* __restrict__ seq,
                                              const float* __restrict__ att,
                                              const int* __restrict__ mpos,
                                              const float* __restrict__ Wh,
                                              const float* __restrict__ Wt,
                                              const float* __restrict__ wbi,
                                              unsigned short* __restrict__ ep,
                                              unsigned short* __restrict__ eatt,
                                              unsigned short* __restrict__ sp,
                                              unsigned short* __restrict__ wp1,
                                              unsigned short* __restrict__ wp2,
                                              _Float16* __restrict__ wbp,
                                              float* __restrict__ out_zero) {
    __shared__ float smem[64 * 97];   // union: 64x65 tiles or 64x97 wbi slab
    int blk = blockIdx.x;
    int t = threadIdx.x;

    if (blk < PB_EATT) {
        // ---- entity logsumexp embeds -> A-pack [11 mt][24 kb] ----
        int be = blk - PB_EMBS, mt = be >> 4, lm = be & 15;
        float vals[3] = {0.f, 0.f, 0.f};
        if (be < BE) {
            int b = be / NEc;
            const int* pp = mpos + be * Mc;
            int p0 = pp[0] + 1, p1 = pp[1] + 1, p2 = pp[2] + 1, p3 = pp[3] + 1;
            const float* s = seq + (size_t)b * Lc * Dc;
            #pragma unroll
            for (int i = 0; i < 3; ++i) {
                int d = t + i * 256;
                float x0 = s[(size_t)p0 * Dc + d], x1 = s[(size_t)p1 * Dc + d];
                float x2 = s[(size_t)p2 * Dc + d], x3 = s[(size_t)p3 * Dc + d];
                float mx = fmaxf(fmaxf(x0, x1), fmaxf(x2, x3));
                vals[i] = mx + logf(expf(x0 - mx) + expf(x1 - mx) + expf(x2 - mx) + expf(x3 - mx));
            }
        }
        #pragma unroll
        for (int i = 0; i < 3; ++i) {
            int d = t + i * 256;
            int idx = ((mt * 24 + (d >> 5)) << 9) + (((d >> 3) & 3) << 7) + (lm << 3) + (d & 7);
            ep[idx] = f2bf(vals[i]);
        }
    } else if (blk < PB_TRSEQ) {
        // ---- entity attention mean -> bf16 [be][h][l] ----
        int idx = blk - PB_EATT;
        int be = idx / Hc, h = idx - be * Hc, b = be / NEc;
        const int* pp = mpos + be * Mc;
        const float* a = att + ((size_t)(b * Hc + h)) * Lc * Lc;
        const float4* r0 = (const float4*)(a + (size_t)(pp[0] + 1) * Lc);
        const float4* r1 = (const float4*)(a + (size_t)(pp[1] + 1) * Lc);
        const float4* r2 = (const float4*)(a + (size_t)(pp[2] + 1) * Lc);
        const float4* r3 = (const float4*)(a + (size_t)(pp[3] + 1) * Lc);
        unsigned short* o = eatt + ((size_t)be * Hc + h) * Lc;
        float4 v0 = r0[t], v1 = r1[t], v2 = r2[t], v3 = r3[t];
        o[t * 4 + 0] = f2bf(0.25f * (v0.x + v1.x + v2.x + v3.x));
        o[t * 4 + 1] = f2bf(0.25f * (v0.y + v1.y + v2.y + v3.y));
        o[t * 4 + 2] = f2bf(0.25f * (v0.z + v1.z + v2.z + v3.z));
        o[t * 4 + 3] = f2bf(0.25f * (v0.w + v1.w + v2.w + v3.w));
    } else if (blk < PB_TRW) {
        // ---- seq [B,L,D] f32 -> B-pack [b][48 nt][32 kb] bf16 (n=d, k=l) ----
        int idx = blk - PB_TRSEQ;
        int xb = idx & 15, yb = (idx >> 4) % 12, b = idx / 192;
        int l0 = xb * 64, d0 = yb * 64;
        const float* s = seq + (size_t)b * Lc * Dc;
        #pragma unroll
        for (int i = 0; i < 16; ++i) {
            int ii = t + i * 256, r = ii >> 6, c = ii & 63;
            smem[r * 65 + c] = s[(size_t)(l0 + r) * Dc + d0 + c];
        }
        __syncthreads();
        unsigned short* outb = sp + (size_t)b * 48 * 32 * 512;
        int flat = t * 2, lane = flat >> 3, j = flat & 7;
        #pragma unroll
        for (int nt_i = 0; nt_i < 4; ++nt_i)
            #pragma unroll
            for (int kb_i = 0; kb_i < 2; ++kb_i) {
                int kl = kb_i * 32 + (lane >> 4) * 8 + j;
                int c  = nt_i * 16 + (lane & 15);
                unsigned int v = (unsigned)f2bf(smem[kl * 65 + c]) |
                                 ((unsigned)f2bf(smem[(kl + 1) * 65 + c]) << 16);
                *(unsigned int*)&outb[(((d0 / 16 + nt_i) * 32 + (l0 / 32 + kb_i)) << 9) + flat] = v;
            }
    } else if (blk < PB_TRWBI) {
        // ---- Wh/Wt [1536][768] -> B-pack wp1/wp2 [96 nt][24 kb] ----
        int idx = blk - PB_TRW;
        int xb = idx % 24, yb = (idx / 24) % 12, which = idx / 288;
        int k0 = xb * 64, n0 = yb * 64;
        const float* W = which ? Wt : Wh;
        #pragma unroll
        for (int i = 0; i < 16; ++i) {
            int ii = t + i * 256, r = ii >> 6, c = ii & 63;
            smem[r * 65 + c] = W[(size_t)(k0 + r) * Dc + n0 + c];
        }
        __syncthreads();
        unsigned short* dst = (k0 < Dc) ? wp1 : wp2;
        int kb0 = ((k0 < Dc) ? k0 : (k0 - Dc)) / 32;
        int nt0 = which * 48 + n0 / 16;
        int flat = t * 2, lane = flat >> 3, j = flat & 7;
        #pragma unroll
        for (int nt_i = 0; nt_i < 4; ++nt_i)
            #pragma unroll
            for (int kb_i = 0; kb_i < 2; ++kb_i) {
                int kl = kb_i * 32 + (lane >> 4) * 8 + j;
                int c  = nt_i * 16 + (lane & 15);
                unsigned int v = (unsigned)f2bf(smem[kl * 65 + c]) |
                                 ((unsigned)f2bf(smem[(kl + 1) * 65 + c]) << 16);
                *(unsigned int*)&dst[(((nt0 + nt_i) * 24 + kb0 + kb_i) << 9) + flat] = v;
            }
    } else if (blk < PB_ZERO) {
        // ---- W_bi [49152,97] f32 -> f16 B-pack [(nt*12+g)*64+x][2 half][512] ----
        int idx = blk - PB_TRWBI;
        int x = idx & 63, g = idx >> 6;
        const float* src = wbi + (size_t)(g * 4096 + x * 64) * NLc;
        for (int i = t; i < 64 * NLc; i += 256) smem[i] = src[i];
        __syncthreads();
        int flat = t * 2, lane = flat >> 3, j = flat & 7;
        int lm = lane & 15, qj = (lane >> 4) * 8 + j;
        #pragma unroll
        for (int nt = 0; nt < 7; ++nt)
            #pragma unroll
            for (int half = 0; half < 2; ++half) {
                int y = half * 32 + qj;
                int n = nt * 16 + lm;
                _Float16 v0 = (n < NLc) ? (_Float16)smem[y * NLc + n] : (_Float16)0.f;
                _Float16 v1 = (n < NLc) ? (_Float16)smem[(y + 1) * NLc + n] : (_Float16)0.f;
                size_t base = ((((size_t)(nt * 12 + g) * 64 + x) * 2 + half) << 9);
                _Float16* d = wbp + base + flat;
                d[0] = v0; d[1] = v1;
            }
    } else {
        // ---- zero d_out (2048*97 f32 = 97 blocks x 2048 floats) ----
        int idx = blk - PB_ZERO;
        float4* o = (float4*)(out_zero + (size_t)idx * 2048);
        float4 z = {0.f, 0.f, 0.f, 0.f};
        o[t] = z;
        o[t + 256] = z;
    }
}

// ---------------------------------------------------------------------------
// pair weights -> A-pack [128 mt][32 kb]
__global__ __launch_bounds__(256) void k_pairw(const unsigned short* __restrict__ eatt,
                                               const int* __restrict__ hts,
                                               unsigned short* __restrict__ pwp) {
    int bp = blockIdx.x, b = bp / Pc;
    int hi = hts[bp * 2], ti = hts[bp * 2 + 1];
    const unsigned short* ai = eatt + ((size_t)(b * NEc + hi)) * Hc * Lc;
    const unsigned short* aj = eatt + ((size_t)(b * NEc + ti)) * Hc * Lc;
    int l0 = threadIdx.x * 4;
    float acc[4] = {0.f, 0.f, 0.f, 0.f};
    #pragma unroll
    for (int h = 0; h < Hc; ++h) {
        uint2 ua = *(const uint2*)(ai + h * Lc + l0);
        uint2 ub = *(const uint2*)(aj + h * Lc + l0);
        acc[0] += bf2f(ua.x & 0xffff) * bf2f(ub.x & 0xffff);
        acc[1] += bf2f(ua.x >> 16)    * bf2f(ub.x >> 16);
        acc[2] += bf2f(ua.y & 0xffff) * bf2f(ub.y & 0xffff);
        acc[3] += bf2f(ua.y >> 16)    * bf2f(ub.y >> 16);
    }
    float lsum = acc[0] + acc[1] + acc[2] + acc[3];
    #pragma unroll
    for (int off = 32; off > 0; off >>= 1) lsum += __shfl_down(lsum, off, 64);
    __shared__ float red[4];
    __shared__ float sinv;
    int lane = threadIdx.x & 63, wv = threadIdx.x >> 6;
    if (lane == 0) red[wv] = lsum;
    __syncthreads();
    if (threadIdx.x == 0) sinv = 1.f / (red[0] + red[1] + red[2] + red[3] + 1.2e-4f);
    __syncthreads();
    float s = sinv;
    unsigned short w0 = f2bf(acc[0] * s), w1 = f2bf(acc[1] * s);
    unsigned short w2 = f2bf(acc[2] * s), w3 = f2bf(acc[3] * s);
    int mt = bp >> 4, lm = bp & 15, kb = l0 >> 5, quad = (l0 >> 3) & 3, j0 = l0 & 7;
    unsigned short* dst = pwp + ((mt * 32 + kb) << 9) + (quad << 7) + (lm << 3) + j0;
    *(uint2*)dst = make_uint2((unsigned)w0 | ((unsigned)w1 << 16),
                              (unsigned)w2 | ((unsigned)w3 << 16));
}

// ---------------------------------------------------------------------------
// fused: k_rs (blocks 0..383) + k_E (blocks 384..647)
__global__ __launch_bounds__(256) void k_rsE(const unsigned short* __restrict__ pwp,
                                             const unsigned short* __restrict__ sp,
                                             const unsigned short* __restrict__ ep,
                                             const unsigned short* __restrict__ wp1,
                                             unsigned short* __restrict__ rsp,
                                             unsigned short* __restrict__ E) {
    int tid = threadIdx.x, wave = tid >> 6, lane = tid & 63;
    int quad = lane >> 4, lm = lane & 15;
    int blk = blockIdx.x;
    if (blk < 384) {
        // rs = pw @ seq -> A-pack [128 mt][24 kb]
        int mb = blk & 7, ntq = (blk >> 3) % 12, b = blk / 96;
        int nt = ntq * 4 + wave;
        int mt0 = b * 32 + mb * 4;
        const unsigned short* bbase = sp + (((size_t)b * 48 + nt) * 32 << 9) + lane * 8;
        const unsigned short* abase = pwp + ((size_t)mt0 * 32 << 9) + lane * 8;
        f32x4 acc[4] = {};
        for (int kb = 0; kb < 32; ++kb) {
            short8 bf = ld8(bbase + kb * 512);
            #pragma unroll
            for (int mf = 0; mf < 4; ++mf)
                acc[mf] = mfma_bf(ld8(abase + (mf * 32 + kb) * 512), bf, acc[mf]);
        }
        int n = nt * 16 + lm, kbo = n >> 5, lq = ((n >> 3) & 3) << 4, jo = n & 7;
        #pragma unroll
        for (int mf = 0; mf < 4; ++mf) {
            unsigned short* db = rsp + (((mt0 + mf) * 24 + kbo) << 9) + jo;
            #pragma unroll
            for (int r = 0; r < 4; ++r)
                db[(lq + quad * 4 + r) << 3] = f2bf(acc[mf][r]);
        }
    } else {
        // E[be][n'] = emb[be] @ [Wh1 | Wt1] -> bf16 [176][1536]
        int idx = blk - 384;
        int mt = idx % 11, ntq = idx / 11;
        int nt = ntq * 4 + wave;
        const unsigned short* ab = ep + (mt * 24 << 9) + lane * 8;
        const unsigned short* bb = wp1 + (nt * 24 << 9) + lane * 8;
        f32x4 acc = {};
        for (int kb = 0; kb < 24; ++kb)
            acc = mfma_bf(ld8(ab + kb * 512), ld8(bb + kb * 512), acc);
        #pragma unroll
        for (int r = 0; r < 4; ++r)
            E[(size_t)(mt * 16 + quad * 4 + r) * N2 + nt * 16 + lm] = f2bf(acc[r]);
    }
}

// ---------------------------------------------------------------------------
// R[row][n'] = rs[row] @ [Wh2 | Wt2] -> bf16 [2048][1536].  grid (32 mb, 24 ntq)
__global__ __launch_bounds__(256) void k_R(const unsigned short* __restrict__ rsp,
                                           const unsigned short* __restrict__ wp2,
                                           unsigned short* __restrict__ R) {
    int tid = threadIdx.x, wave = tid >> 6, lane = tid & 63;
    int quad = lane >> 4, lm = lane & 15;
    int mt0 = blockIdx.x * 4, nt = blockIdx.y * 4 + wave;
    const unsigned short* bb = wp2 + (nt * 24 << 9) + lane * 8;
    const unsigned short* ab = rsp + ((size_t)mt0 * 24 << 9) + lane * 8;
    f32x4 acc[4] = {};
    for (int kb = 0; kb < 24; ++kb) {
        short8 bf = ld8(bb + kb * 512);
        #pragma unroll
        for (int mf = 0; mf < 4; ++mf)
            acc[mf] = mfma_bf(ld8(ab + (mf * 24 + kb) * 512), bf, acc[mf]);
    }
    #pragma unroll
    for (int mf = 0; mf < 4; ++mf)
        #pragma unroll
        for (int r = 0; r < 4; ++r)
            R[(size_t)((mt0 + mf) * 16 + quad * 4 + r) * N2 + nt * 16 + lm] = f2bf(acc[mf][r]);
}

// ---------------------------------------------------------------------------
// zs = tanh(E_h + R_h + bh) -> f16 row-major; zo = tanh(E_t + R_t + bt) -> f16 A-pack
__global__ __launch_bounds__(256) void k_zfin(const unsigned short* __restrict__ E,
                                              const unsigned short* __restrict__ R,
                                              const int* __restrict__ hts,
                                              const float* __restrict__ bh,
                                              const float* __restrict__ bt,
                                              _Float16* __restrict__ zs,
                                              _Float16* __restrict__ zop) {
    int row = blockIdx.x, b = row >> 9;
    int hh = hts[row * 2], tt = hts[row * 2 + 1];
    const unsigned short* Eh = E + (size_t)(b * NEc + hh) * N2;
    const unsigned short* Et = E + (size_t)(b * NEc + tt) * N2 + Dc;
    const unsigned short* Rr = R + (size_t)row * N2;
    #pragma unroll
    for (int i = 0; i < 3; ++i) {
        int n = threadIdx.x + i * 256;
        float vs = tanhf(bf2f(Eh[n]) + bf2f(Rr[n]) + bh[n]);
        float vo = tanhf(bf2f(Et[n]) + bf2f(Rr[Dc + n]) + bt[n]);
        zs[(size_t)row * Dc + n] = (_Float16)vs;
        int idx = (((row >> 4) * 24 + (n >> 5)) << 9) + (((((n >> 3) & 3) << 4) + (row & 15)) << 3) + (n & 7);
        zop[idx] = (_Float16)vo;
    }
}

// ---------------------------------------------------------------------------
// grouped bilinear: out[row,n] += sum_{x,y} zs[row,gx] zo[row,gy] W[g,x,y,n]
// grid (8 pb, 7 nt, 12 g), 4 waves; wave: M=64, N=16 (zs folded into A in f16)
__global__ __launch_bounds__(256) void k_bilin(const _Float16* __restrict__ zs,
                                               const _Float16* __restrict__ zop,
                                               const _Float16* __restrict__ wbp,
                                               const float* __restrict__ bbi,
                                               float* __restrict__ out) {
    __shared__ _Float16 zlds[256 * 72];
    int tid = threadIdx.x, wave = tid >> 6, lane = tid & 63;
    int quad = lane >> 4, lm = lane & 15;
    int pb = blockIdx.x, nt = blockIdx.y, g = blockIdx.z;
    {
        const half8* src = (const half8*)(zs + ((size_t)(pb * 256 + tid)) * Dc + g * 64);
        half8* dst = (half8*)&zlds[tid * 72];
        #pragma unroll
        for (int c = 0; c < 8; ++c) dst[c] = src[c];   // 64 halves = full group slice
    }
    __syncthreads();
    int mt0 = pb * 16 + wave * 4;
    half8 zofr[4][2];
    #pragma unroll
    for (int mf = 0; mf < 4; ++mf)
        #pragma unroll
        for (int hf = 0; hf < 2; ++hf)
            zofr[mf][hf] = ldh8(zop + (((mt0 + mf) * 24 + g * 2 + hf) << 9) + lane * 8);
    const _Float16* wbase = wbp + ((size_t)(nt * 12 + g) << 16) + lane * 8;
    const _Float16* zrow = &zlds[(wave * 64 + lm) * 72];
    f32x4 acc[4] = {};
    for (int x = 0; x < 64; ++x) {
        half8 b0 = ldh8(wbase + x * 1024);
        half8 b1 = ldh8(wbase + x * 1024 + 512);
        #pragma unroll
        for (int mf = 0; mf < 4; ++mf) {
            _Float16 s = zrow[mf * 16 * 72 + x];
            half8 bc = {s, s, s, s, s, s, s, s};
            acc[mf] = mfma_h(bc * zofr[mf][0], b0, acc[mf]);
            acc[mf] = mfma_h(bc * zofr[mf][1], b1, acc[mf]);
        }
    }
    int n = nt * 16 + lm;
    if (n < NLc) {
        #pragma unroll
        for (int mf = 0; mf < 4; ++mf)
            #pragma unroll
            for (int r = 0; r < 4; ++r) {
                int row = (mt0 + mf) * 16 + quad * 4 + r;
                float v = acc[mf][r];
                if (g == 0) v += bbi[n];
                atomicAdd(out + (size_t)row * NLc + n, v);
            }
    }
}

// ---------------------------------------------------------------------------
extern "C" void kernel_launch(void* const* d_in, const int* in_sizes, int n_in,
                              void* d_out, int out_size, void* d_ws, size_t ws_size,
                              hipStream_t stream) {
    const float* seq  = (const float*)d_in[0];
    const float* att  = (const float*)d_in[1];
    const int*   mpos = (const int*)d_in[2];
    const int*   hts  = (const int*)d_in[3];
    const float* Wh   = (const float*)d_in[4];
    const float* bh   = (const float*)d_in[5];
    const float* Wt   = (const float*)d_in[6];
    const float* bt   = (const float*)d_in[7];
    const float* Wbi  = (const float*)d_in[8];
    const float* bbi  = (const float*)d_in[9];
    float* out = (float*)d_out;

    // Workspace layout (no overlays this round — everything live simultaneously)
    char* w = (char*)d_ws;
    unsigned short* embs_p = (unsigned short*)(w);                 //   270,336
    unsigned short* eatt_b = (unsigned short*)(w + 270336);        // 4,128,768
    unsigned short* pw_p   = (unsigned short*)(w + 4399104);       // 4,194,304
    unsigned short* seq_p  = (unsigned short*)(w + 8593408);       // 6,291,456
    _Float16*       wbi_p  = (_Float16*)(w + 14884864);            // 11,010,048
    unsigned short* wp1    = (unsigned short*)(w + 25894912);      // 2,359,296
    unsigned short* wp2    = (unsigned short*)(w + 28254208);      // 2,359,296
    unsigned short* E      = (unsigned short*)(w + 30613504);      //   540,672
    unsigned short* rs_p   = (unsigned short*)(w + 31154176);      // 3,145,728
    unsigned short* R      = (unsigned short*)(w + 34299904);      // 6,291,456
    _Float16*       zs     = (_Float16*)(w + 40591360);            // 3,145,728
    _Float16*       zo_p   = (_Float16*)(w + 43737088);            // 3,145,728
    // total 46,882,816 B

    k_prep <<<PB_TOTAL, 256, 0, stream>>>(seq, att, mpos, Wh, Wt, Wbi,
                                          embs_p, eatt_b, seq_p, wp1, wp2, wbi_p, out);
    k_pairw<<<ROWS, 256, 0, stream>>>(eatt_b, hts, pw_p);
    k_rsE  <<<648, 256, 0, stream>>>(pw_p, seq_p, embs_p, wp1, rs_p, E);
    k_R    <<<dim3(32, 24), 256, 0, stream>>>(rs_p, wp2, R);
    k_zfin <<<ROWS, 256, 0, stream>>>(E, R, hts, bh, bt, zs, zo_p);
    k_bilin<<<dim3(8, 7, 12), 256, 0, stream>>>(zs, zo_p, wbi_p, bbi, out);
}